// Round 10
// baseline (307.763 us; speedup 1.0000x reference)
//
#include <hip/hip_runtime.h>

typedef __bf16 bf16x8 __attribute__((ext_vector_type(8)));
typedef float f32x4 __attribute__((ext_vector_type(4)));

#define LOG2E 1.4426950408889634f
#define NEGC (-12.0f * LOG2E)   // fixed softmax cap C=12 in log2 units

__device__ inline unsigned short f2bf(float f) {
  unsigned int u = __builtin_bit_cast(unsigned int, f);
  u += 0x7fff + ((u >> 16) & 1);
  return (unsigned short)(u >> 16);
}

__device__ inline void async16(const void* g, void* l) {
  __builtin_amdgcn_global_load_lds(
      (__attribute__((address_space(1))) void*)(g),
      (__attribute__((address_space(3))) void*)(l), 16, 0, 0);
}

// One launch for all f32->bf16 casts: blocks [0,8192) cover x (8M elems),
// blocks [8192,12288) cover the 4 weight matrices (1M elems each).
__global__ __launch_bounds__(256) void cast_all(
    const float* __restrict__ x, const float* __restrict__ w0,
    const float* __restrict__ w1, const float* __restrict__ w2,
    const float* __restrict__ w3, unsigned short* __restrict__ xb,
    unsigned short* __restrict__ ob /* 4 contiguous 1M outputs */) {
  int id = blockIdx.x;
  const float* in;
  unsigned short* out;
  int boff;
  if (id < 8192) { in = x; out = xb; boff = id; }
  else {
    int w = (id - 8192) >> 10; boff = (id - 8192) & 1023;
    switch (w) { case 0: in = w0; break; case 1: in = w1; break;
                 case 2: in = w2; break; default: in = w3; }
    out = ob + (long)w * 1048576;
  }
  int i = (boff * 256 + threadIdx.x) * 4;
  float4 v = *(const float4*)(in + i);
  ushort4 o;
  o.x = f2bf(v.x); o.y = f2bf(v.y); o.z = f2bf(v.z); o.w = f2bf(v.w);
  *(ushort4*)(out + i) = o;
}

// ---------------------------------------------------------------------------
// 128x128 GEMM (m97 2-barrier structure), harness-proven. QKV (mode 4) and
// final projection (mode 0).
// C[M,N] = A[M,K] * W[N,K]^T, bf16 in. Launched 1-D; M/BM must be 64.
// mode 0: f32 row-major [M,N]
// mode 4: fused QKV scatter. Q (x0.125) and K -> [B,H,S,D]. V -> V^T [B,H,D,S].
// r6: Q/K epilogue bounces through LDS (aliases dead As/Ws) -> uint4 stores.
// r7 counters: dropped out of top-5 (dur < 74us) -> keep.
// ---------------------------------------------------------------------------
#define BM 128
#define BN 128
#define BK 32

__global__ __launch_bounds__(256, 3) void gemm_bt(
    const unsigned short* __restrict__ A, const unsigned short* __restrict__ W,
    void* __restrict__ out, int M, int N, int K, int mode) {
  __shared__ unsigned short SM[BM * BK + BN * BK];  // As | Ws, 16 KB total
  unsigned short* As = SM;
  unsigned short* Ws = SM + BM * BK;
  int tid = threadIdx.x;
  int lane = tid & 63, wid = tid >> 6;
  int wm = wid >> 1, wn = wid & 1;
  int l15 = lane & 15, quad = lane >> 4;
  int m0 = (blockIdx.x & 63) * BM, n0 = (blockIdx.x >> 6) * BN;

  f32x4 acc[4][4] = {};

  int srow = tid >> 2;         // 0..63
  int scol = (tid & 3) * 8;    // 0,8,16,24
  const unsigned short* Ag = A + (long)(m0 + srow) * K + scol;
  const unsigned short* Wg = W + (long)(n0 + srow) * K + scol;
  char* AsB = (char*)As + wid * 1024;   // + lane*16 implicit in global_load_lds
  char* WsB = (char*)Ws + wid * 1024;

  for (int kt = 0; kt < K; kt += BK) {
    __syncthreads();
    async16(Ag + kt, AsB);
    async16(Ag + kt + (long)64 * K, AsB + 4096);
    async16(Wg + kt, WsB);
    async16(Wg + kt + (long)64 * K, WsB + 4096);
    __syncthreads();
    bf16x8 af[4], wf[4];
#pragma unroll
    for (int t = 0; t < 4; t++)
      af[t] = *(const bf16x8*)(As + (wm * 64 + t * 16 + l15) * BK + quad * 8);
#pragma unroll
    for (int t = 0; t < 4; t++)
      wf[t] = *(const bf16x8*)(Ws + (wn * 64 + t * 16 + l15) * BK + quad * 8);
#pragma unroll
    for (int i = 0; i < 4; i++)
#pragma unroll
      for (int j = 0; j < 4; j++)
        acc[i][j] = __builtin_amdgcn_mfma_f32_16x16x32_bf16(af[i], wf[j], acc[i][j], 0, 0, 0);
  }

  if (mode == 0) {
    float* Cf = (float*)out;
#pragma unroll
    for (int i = 0; i < 4; i++) {
      int row = m0 + wm * 64 + i * 16 + quad * 4;
#pragma unroll
      for (int j = 0; j < 4; j++) {
        int col = n0 + wn * 64 + j * 16 + l15;
#pragma unroll
        for (int r = 0; r < 4; r++)
          Cf[(long)(row + r) * N + col] = acc[i][j][r];
      }
    }
  } else {
    unsigned short* Cb = (unsigned short*)out;
    int which = n0 >> 10;   // block lies entirely in one of Q/K/V
    if (which == 2) {
      // V -> V^T [B,H,D,S]: packed 4-consecutive-s stores (8B/lane)
#pragma unroll
      for (int i = 0; i < 4; i++)
#pragma unroll
        for (int j = 0; j < 4; j++) {
          int m = m0 + wm * 64 + i * 16 + quad * 4;
          int n = n0 + wn * 64 + j * 16 + l15;
          int nn = n & 1023;
          int b = m >> 11, s = m & 2047;   // S = 2048 (block never crosses b)
          int h = nn >> 6, d = nn & 63;    // D = 64
          ushort4 pk;
          pk.x = f2bf(acc[i][j][0]); pk.y = f2bf(acc[i][j][1]);
          pk.z = f2bf(acc[i][j][2]); pk.w = f2bf(acc[i][j][3]);
          *(ushort4*)(&Cb[16777216 + (((long)((b * 16 + h) * 64 + d)) << 11) + s]) = pk;
        }
    } else {
      // Q/K -> [B,H,S,D] via LDS bounce (quarters of 32 rows through SM).
      float scale = (which == 0) ? 0.125f : 1.0f;
      int h0 = (n0 & 1023) >> 6;
      unsigned short* Es = SM;    // 32 x 136 = 8704 B, aliases dead As/Ws
#pragma unroll
      for (int qr = 0; qr < 4; qr++) {
        __syncthreads();          // K-loop / previous quarter reads done
        if (wm == (qr >> 1)) {    // wave-uniform predicate
#pragma unroll
          for (int ii = 0; ii < 2; ii++) {
            int i = (qr & 1) * 2 + ii;      // rows wm*64 + i*16 + .. in quarter
#pragma unroll
            for (int j = 0; j < 4; j++)
#pragma unroll
              for (int r = 0; r < 4; r++) {
                int rr = (i & 1) * 16 + quad * 4 + r;   // row within quarter
                Es[rr * 136 + wn * 64 + j * 16 + l15] = f2bf(acc[i][j][r] * scale);
              }
          }
        }
        __syncthreads();
#pragma unroll
        for (int p = 0; p < 2; p++) {
          int pair = p * 32 + (tid >> 3);   // 0..63: (row-in-quarter, head)
          int rq = pair >> 1;
          int head = pair & 1, c8 = tid & 7;
          uint4 v = *(const uint4*)(&Es[rq * 136 + head * 64 + c8 * 8]);
          int m = m0 + qr * 32 + rq;
          int b = m >> 11, s = m & 2047;    // S = 2048
          int h = h0 + head;
          long idx = (long)which * 8388608 +
                     ((long)((b * 16 + h) * 2048 + s)) * 64 + c8 * 8;
          *(uint4*)(&Cb[idx]) = v;
        }
      }
    }
  }
}

// ---------------------------------------------------------------------------
// Flash attention, causal + pad mask, fixed softmax cap (scores bounded ~±7).
// Q prescaled by 1/sqrt(D). Q,K: [B*H, S, 64] bf16 ; VT: [B*H, 64, S] bf16 ;
// O: [B*S, 1024] bf16.
//
// r7 post-mortem: heavy-first reorder raised occupancy 21->25 but dur pinned
// at 74us -> latency-bound on the per-tile serial chain (2 barriers + V LDS
// round-trip). r8 restructure:
//  * Ks double-buffered in LDS -> ONE barrier per kv-tile (write Ks[nxt]
//    before reading Ks[cur]; barrier after QK. WAR/RAW separated by the
//    previous iteration's barrier.)
//  * V never staged to LDS: PV B-fragments (8 x 16B/thread) loaded directly
//    from global VT into regs one tile ahead (L2-resident: 8KB tile reused
//    by 16 q-blocks/head). Kills V's LDS write+read and the second barrier.
//  * LDS: Ks[2] 19KB + QPs 19KB = 38912B — identical footprint, 3 blk/CU.
// ---------------------------------------------------------------------------
#define BQ 128
#define BKV 64
#define PSTR 76   // 38 dwords/row: quads land on banks +0/24/16/8 -> 2-way max

__global__ __launch_bounds__(256, 3) void attn(
    const unsigned short* __restrict__ Q, const unsigned short* __restrict__ Kt,
    const unsigned short* __restrict__ VT, const int* __restrict__ am,
    unsigned short* __restrict__ O) {
  __shared__ unsigned short QPs[BQ * PSTR];     // 19 KB: Q tile, then per-wave P, then O bounce
  __shared__ unsigned short Ks[2][BKV * PSTR];  // 19 KB: double-buffered K tile
  const int S = 2048, D = 64;
  int tid = threadIdx.x, lane = tid & 63, wid = tid >> 6;
  int l15 = lane & 15, quad = lane >> 4;

  int id = blockIdx.x;
  int s = id >> 8;          // CU slot
  int r = id & 255;
  int bh = r & 63;
  int c = r >> 6;           // 0..3
  int qt;                   // heavy-first: s=0 gets the deepest q-tiles
  switch (s) { case 0: qt = 15 - c; break; case 1: qt = 8 + c; break;
               case 2: qt = 7 - c; break; default: qt = c; }
  int q0 = qt * BQ;
  int b = bh >> 4, h = bh & 15;
  const unsigned short* Qg = Q + (long)bh * S * D;
  const unsigned short* Kg = Kt + (long)bh * S * D;
  const unsigned short* Vg = VT + (long)bh * D * S;
  const int* amg = am + b * S;

  // staging geometry (Q prologue and K loop)
  int row0 = tid >> 3, col0 = (tid & 7) * 8;          // rows 0..31
  int row1 = 32 + (tid >> 3), col1 = col0;            // rows 32..63

  // stage Q tile [128][64] -> padded LDS
#pragma unroll
  for (int rr = 0; rr < 4; rr++) {
    int cc = rr * 256 + tid;
    int row = cc >> 3, col = (cc & 7) * 8;
    *(uint4*)(&QPs[row * PSTR + col]) = *(const uint4*)(Qg + (long)(q0 + row) * D + col);
  }

  // prefetch K tile 0 into registers (overlaps the Q barrier)
  uint4 kreg0 = *(const uint4*)(Kg + (long)row0 * D + col0);
  uint4 kreg1 = *(const uint4*)(Kg + (long)row1 * D + col1);

  __syncthreads();
  bf16x8 qf[2][2];   // each wave reads ONLY its own 32-row slab -> safe to alias P later
#pragma unroll
  for (int i = 0; i < 2; i++)
#pragma unroll
    for (int kk = 0; kk < 2; kk++)
      qf[i][kk] = *(const bf16x8*)(&QPs[(wid * 32 + i * 16 + l15) * PSTR + kk * 32 + quad * 8]);

  // Ks[0] <- tile 0; prefetch K tile 1 regs; V tile 0 fragments direct to regs
  *(uint4*)(&Ks[0][row0 * PSTR + col0]) = kreg0;
  *(uint4*)(&Ks[0][row1 * PSTR + col1]) = kreg1;
  kreg0 = *(const uint4*)(Kg + (long)(BKV + row0) * D + col0);
  kreg1 = *(const uint4*)(Kg + (long)(BKV + row1) * D + col1);
  bf16x8 vf[2][4];
#pragma unroll
  for (int kk = 0; kk < 2; kk++)
#pragma unroll
    for (int j = 0; j < 4; j++)
      vf[kk][j] = *(const bf16x8*)(Vg + (long)(j * 16 + l15) * S + kk * 32 + quad * 8);
  __syncthreads();   // Ks[0] visible to all waves

  f32x4 o_acc[2][4] = {};
  float lsum[2][4] = {};   // per-lane partials; reduced once in epilogue

  int tFull = q0 >> 6;          // tiles strictly below the diagonal
  int nt = tFull + 2;           // + 2 diagonal tiles
  for (int t = 0; t < nt; t++) {
    int s0 = t * BKV;
    int cur = t & 1, nxt = cur ^ 1;

    // 1: write NEXT K tile into the alternate buffer (kreg holds tile t+1).
    //    Safe: that buffer's last readers were iter t-1's QK, behind its barrier.
    *(uint4*)(&Ks[nxt][row0 * PSTR + col0]) = kreg0;
    *(uint4*)(&Ks[nxt][row1 * PSTR + col1]) = kreg1;

    // pad-mask bias loads issued before MFMA so they hide under it
    int mvj[4];
#pragma unroll
    for (int j = 0; j < 4; j++) mvj[j] = amg[s0 + j * 16 + l15];

    // 2: S = Q K^T from Ks[cur] (written iter t-1, behind its barrier)
    f32x4 sacc[2][4] = {};
#pragma unroll
    for (int kk = 0; kk < 2; kk++) {
      bf16x8 kf[4];
#pragma unroll
      for (int j = 0; j < 4; j++)
        kf[j] = *(const bf16x8*)(&Ks[cur][(j * 16 + l15) * PSTR + kk * 32 + quad * 8]);
      __builtin_amdgcn_s_setprio(1);
#pragma unroll
      for (int i = 0; i < 2; i++)
#pragma unroll
        for (int j = 0; j < 4; j++)
          sacc[i][j] = __builtin_amdgcn_mfma_f32_16x16x32_bf16(qf[i][kk], kf[j], sacc[i][j], 0, 0, 0);
      __builtin_amdgcn_s_setprio(0);
    }

    // 3: the ONLY barrier of the iteration (all QK reads of Ks[cur] done;
    //    next iter may overwrite it).
    __syncthreads();

    // 4: prefetch K tile t+2 into regs (clamped; landed by next iter's write)
    {
      long s0n = (long)(t + 2) * BKV; if (s0n > S - BKV) s0n = S - BKV;
      kreg0 = *(const uint4*)(Kg + (s0n + row0) * D + col0);
      kreg1 = *(const uint4*)(Kg + (s0n + row1) * D + col1);
    }

    float fb[4];
#pragma unroll
    for (int j = 0; j < 4; j++) fb[j] = mvj[j] ? NEGC : -1e38f;

    // 5: softmax -> per-wave P slab (no cross-wave hazard)
    if (t < tFull) {
#pragma unroll
      for (int i = 0; i < 2; i++)
#pragma unroll
        for (int rr = 0; rr < 4; rr++) {
          int prow = (wid * 32 + i * 16 + quad * 4 + rr) * PSTR;
          float rs = 0.f;
#pragma unroll
          for (int j = 0; j < 4; j++) {
            float p = __builtin_amdgcn_exp2f(fmaf(sacc[i][j][rr], LOG2E, fb[j]));
            unsigned int u = __builtin_bit_cast(unsigned int, p);
            QPs[prow + j * 16 + l15] = (unsigned short)(u >> 16);
            rs += __builtin_bit_cast(float, u & 0xffff0000u);
          }
          lsum[i][rr] += rs;
        }
    } else {
      // diagonal tile: per-element causal mask
#pragma unroll
      for (int i = 0; i < 2; i++)
#pragma unroll
        for (int rr = 0; rr < 4; rr++) {
          int row = q0 + wid * 32 + i * 16 + quad * 4 + rr;
          int prow = (wid * 32 + i * 16 + quad * 4 + rr) * PSTR;
          float rs = 0.f;
#pragma unroll
          for (int j = 0; j < 4; j++) {
            int col = s0 + j * 16 + l15;
            float fbe = (col > row) ? -1e38f : fb[j];
            float p = __builtin_amdgcn_exp2f(fmaf(sacc[i][j][rr], LOG2E, fbe));
            unsigned int u = __builtin_bit_cast(unsigned int, p);
            QPs[prow + j * 16 + l15] = (unsigned short)(u >> 16);
            rs += __builtin_bit_cast(float, u & 0xffff0000u);
          }
          lsum[i][rr] += rs;
        }
    }

    // 6: O += P @ V  (P LDS round-trip; V fragments already in regs)
#pragma unroll
    for (int kk = 0; kk < 2; kk++) {
      bf16x8 pf[2];
#pragma unroll
      for (int i = 0; i < 2; i++)
        pf[i] = *(const bf16x8*)(&QPs[(wid * 32 + i * 16 + l15) * PSTR + kk * 32 + quad * 8]);
      __builtin_amdgcn_s_setprio(1);
#pragma unroll
      for (int i = 0; i < 2; i++)
#pragma unroll
        for (int j = 0; j < 4; j++)
          o_acc[i][j] = __builtin_amdgcn_mfma_f32_16x16x32_bf16(pf[i], vf[kk][j], o_acc[i][j], 0, 0, 0);
      __builtin_amdgcn_s_setprio(0);
    }

    // 7: load V fragments for tile t+1 (clamped); latency hides under the
    //    next iteration's K-write + QK + barrier + softmax.
    {
      long s0v = (long)(t + 1) * BKV; if (s0v > S - BKV) s0v = S - BKV;
#pragma unroll
      for (int kk = 0; kk < 2; kk++)
#pragma unroll
        for (int j = 0; j < 4; j++)
          vf[kk][j] = *(const bf16x8*)(Vg + (long)(j * 16 + l15) * S + s0v + kk * 32 + quad * 8);
    }
  }

  // epilogue: reduce lsum across the 16 col-lanes, normalize, bounce through
  // LDS (P layout), then bulk-store full 128B lines.
#pragma unroll
  for (int i = 0; i < 2; i++)
#pragma unroll
    for (int rr = 0; rr < 4; rr++) {
      float tsum = lsum[i][rr];
      tsum += __shfl_xor(tsum, 1, 64);
      tsum += __shfl_xor(tsum, 2, 64);
      tsum += __shfl_xor(tsum, 4, 64);
      tsum += __shfl_xor(tsum, 8, 64);
      float inv = 1.0f / tsum;
      int prow = (wid * 32 + i * 16 + quad * 4 + rr) * PSTR;
#pragma unroll
      for (int j = 0; j < 4; j++)
        QPs[prow + j * 16 + l15] = f2bf(o_acc[i][j][rr] * inv);
    }
  __syncthreads();
#pragma unroll
  for (int rr = 0; rr < 4; rr++) {
    int cc = rr * 256 + tid;
    int row = cc >> 3, col = (cc & 7) * 8;
    uint4 v = *(const uint4*)(&QPs[row * PSTR + col]);
    long gm = (long)b * S + q0 + row;
    *(uint4*)(&O[gm * 1024 + h * 64 + col]) = v;
  }
}

extern "C" void kernel_launch(void* const* d_in, const int* in_sizes, int n_in,
                              void* d_out, int out_size, void* d_ws, size_t ws_size,
                              hipStream_t stream) {
  const float* x  = (const float*)d_in[0];
  const int*   am = (const int*)d_in[1];
  const float* wq = (const float*)d_in[2];
  const float* wk = (const float*)d_in[3];
  const float* wv = (const float*)d_in[4];
  const float* wo = (const float*)d_in[5];
  float* out = (float*)d_out;

  const int S = 2048, E = 1024, Bb = 4, H = 16;
  const int M = Bb * S;  // 8192

  char* ws = (char*)d_ws;
  unsigned short* xb  = (unsigned short*)ws;                    // 16 MiB
  unsigned short* wqb = (unsigned short*)(ws + 16777216);       // 2 MiB each, contiguous
  unsigned short* wob = wqb + 3 * 1048576;
  unsigned short* Qb  = (unsigned short*)(ws + 25165824);       // Q,K,VT contiguous 16 MiB each
  unsigned short* Ob  = Qb + 25165824;                          // end: 88 MiB

  // all casts in one launch: x (8192 blocks) + 4 weights (1024 each)
  cast_all<<<12288, 256, 0, stream>>>(x, wq, wk, wv, wo, xb, wqb);

  // fused QKV projection: W = [wq;wk;wv] contiguous, N=3072 (1-D swizzled grid).
  gemm_bt<<<dim3((3 * E / BN) * (M / BM)), 256, 0, stream>>>(xb, wqb, Qb, M, 3 * E, E, 4);
  attn<<<dim3(1024), 256, 0, stream>>>(Qb, Qb + 8388608, Qb + 16777216, am, Ob);
  gemm_bt<<<dim3((E / BN) * (M / BM)), 256, 0, stream>>>(Ob, wob, out, M, E, E, 0);  // final proj, f32
}

// Round 11
// 275.705 us; speedup vs baseline: 1.1163x; 1.1163x over previous
//
#include <hip/hip_runtime.h>

typedef __bf16 bf16x8 __attribute__((ext_vector_type(8)));
typedef float f32x4 __attribute__((ext_vector_type(4)));

#define LOG2E 1.4426950408889634f
#define NEGC (-12.0f * LOG2E)   // fixed softmax cap C=12 in log2 units

__device__ inline unsigned short f2bf(float f) {
  unsigned int u = __builtin_bit_cast(unsigned int, f);
  u += 0x7fff + ((u >> 16) & 1);
  return (unsigned short)(u >> 16);
}

__device__ inline void async16(const void* g, void* l) {
  __builtin_amdgcn_global_load_lds(
      (__attribute__((address_space(1))) void*)(g),
      (__attribute__((address_space(3))) void*)(l), 16, 0, 0);
}

// One launch for all f32->bf16 casts: blocks [0,8192) cover x (8M elems),
// blocks [8192,12288) cover the 4 weight matrices (1M elems each).
__global__ __launch_bounds__(256) void cast_all(
    const float* __restrict__ x, const float* __restrict__ w0,
    const float* __restrict__ w1, const float* __restrict__ w2,
    const float* __restrict__ w3, unsigned short* __restrict__ xb,
    unsigned short* __restrict__ ob /* 4 contiguous 1M outputs */) {
  int id = blockIdx.x;
  const float* in;
  unsigned short* out;
  int boff;
  if (id < 8192) { in = x; out = xb; boff = id; }
  else {
    int w = (id - 8192) >> 10; boff = (id - 8192) & 1023;
    switch (w) { case 0: in = w0; break; case 1: in = w1; break;
                 case 2: in = w2; break; default: in = w3; }
    out = ob + (long)w * 1048576;
  }
  int i = (boff * 256 + threadIdx.x) * 4;
  float4 v = *(const float4*)(in + i);
  ushort4 o;
  o.x = f2bf(v.x); o.y = f2bf(v.y); o.z = f2bf(v.z); o.w = f2bf(v.w);
  *(ushort4*)(out + i) = o;
}

// ---------------------------------------------------------------------------
// 128x128 GEMM (m97 2-barrier structure), harness-proven. QKV (mode 4) and
// final projection (mode 0).
// C[M,N] = A[M,K] * W[N,K]^T, bf16 in. Launched 1-D; M/BM must be 64.
// mode 0: f32 row-major [M,N]
// mode 4: fused QKV scatter. Q (x0.125) and K -> [B,H,S,D]. V -> V^T [B,H,D,S].
// r6: Q/K epilogue bounces through LDS (aliases dead As/Ws) -> uint4 stores.
// r7 counters: dropped out of top-5 (dur < 74us) -> keep.
// ---------------------------------------------------------------------------
#define BM 128
#define BN 128
#define BK 32

__global__ __launch_bounds__(256, 3) void gemm_bt(
    const unsigned short* __restrict__ A, const unsigned short* __restrict__ W,
    void* __restrict__ out, int M, int N, int K, int mode) {
  __shared__ unsigned short SM[BM * BK + BN * BK];  // As | Ws, 16 KB total
  unsigned short* As = SM;
  unsigned short* Ws = SM + BM * BK;
  int tid = threadIdx.x;
  int lane = tid & 63, wid = tid >> 6;
  int wm = wid >> 1, wn = wid & 1;
  int l15 = lane & 15, quad = lane >> 4;
  int m0 = (blockIdx.x & 63) * BM, n0 = (blockIdx.x >> 6) * BN;

  f32x4 acc[4][4] = {};

  int srow = tid >> 2;         // 0..63
  int scol = (tid & 3) * 8;    // 0,8,16,24
  const unsigned short* Ag = A + (long)(m0 + srow) * K + scol;
  const unsigned short* Wg = W + (long)(n0 + srow) * K + scol;
  char* AsB = (char*)As + wid * 1024;   // + lane*16 implicit in global_load_lds
  char* WsB = (char*)Ws + wid * 1024;

  for (int kt = 0; kt < K; kt += BK) {
    __syncthreads();
    async16(Ag + kt, AsB);
    async16(Ag + kt + (long)64 * K, AsB + 4096);
    async16(Wg + kt, WsB);
    async16(Wg + kt + (long)64 * K, WsB + 4096);
    __syncthreads();
    bf16x8 af[4], wf[4];
#pragma unroll
    for (int t = 0; t < 4; t++)
      af[t] = *(const bf16x8*)(As + (wm * 64 + t * 16 + l15) * BK + quad * 8);
#pragma unroll
    for (int t = 0; t < 4; t++)
      wf[t] = *(const bf16x8*)(Ws + (wn * 64 + t * 16 + l15) * BK + quad * 8);
#pragma unroll
    for (int i = 0; i < 4; i++)
#pragma unroll
      for (int j = 0; j < 4; j++)
        acc[i][j] = __builtin_amdgcn_mfma_f32_16x16x32_bf16(af[i], wf[j], acc[i][j], 0, 0, 0);
  }

  if (mode == 0) {
    float* Cf = (float*)out;
#pragma unroll
    for (int i = 0; i < 4; i++) {
      int row = m0 + wm * 64 + i * 16 + quad * 4;
#pragma unroll
      for (int j = 0; j < 4; j++) {
        int col = n0 + wn * 64 + j * 16 + l15;
#pragma unroll
        for (int r = 0; r < 4; r++)
          Cf[(long)(row + r) * N + col] = acc[i][j][r];
      }
    }
  } else {
    unsigned short* Cb = (unsigned short*)out;
    int which = n0 >> 10;   // block lies entirely in one of Q/K/V
    if (which == 2) {
      // V -> V^T [B,H,D,S]: packed 4-consecutive-s stores (8B/lane)
#pragma unroll
      for (int i = 0; i < 4; i++)
#pragma unroll
        for (int j = 0; j < 4; j++) {
          int m = m0 + wm * 64 + i * 16 + quad * 4;
          int n = n0 + wn * 64 + j * 16 + l15;
          int nn = n & 1023;
          int b = m >> 11, s = m & 2047;   // S = 2048 (block never crosses b)
          int h = nn >> 6, d = nn & 63;    // D = 64
          ushort4 pk;
          pk.x = f2bf(acc[i][j][0]); pk.y = f2bf(acc[i][j][1]);
          pk.z = f2bf(acc[i][j][2]); pk.w = f2bf(acc[i][j][3]);
          *(ushort4*)(&Cb[16777216 + (((long)((b * 16 + h) * 64 + d)) << 11) + s]) = pk;
        }
    } else {
      // Q/K -> [B,H,S,D] via LDS bounce (quarters of 32 rows through SM).
      float scale = (which == 0) ? 0.125f : 1.0f;
      int h0 = (n0 & 1023) >> 6;
      unsigned short* Es = SM;    // 32 x 136 = 8704 B, aliases dead As/Ws
#pragma unroll
      for (int qr = 0; qr < 4; qr++) {
        __syncthreads();          // K-loop / previous quarter reads done
        if (wm == (qr >> 1)) {    // wave-uniform predicate
#pragma unroll
          for (int ii = 0; ii < 2; ii++) {
            int i = (qr & 1) * 2 + ii;      // rows wm*64 + i*16 + .. in quarter
#pragma unroll
            for (int j = 0; j < 4; j++)
#pragma unroll
              for (int r = 0; r < 4; r++) {
                int rr = (i & 1) * 16 + quad * 4 + r;   // row within quarter
                Es[rr * 136 + wn * 64 + j * 16 + l15] = f2bf(acc[i][j][r] * scale);
              }
          }
        }
        __syncthreads();
#pragma unroll
        for (int p = 0; p < 2; p++) {
          int pair = p * 32 + (tid >> 3);   // 0..63: (row-in-quarter, head)
          int rq = pair >> 1;
          int head = pair & 1, c8 = tid & 7;
          uint4 v = *(const uint4*)(&Es[rq * 136 + head * 64 + c8 * 8]);
          int m = m0 + qr * 32 + rq;
          int b = m >> 11, s = m & 2047;    // S = 2048
          int h = h0 + head;
          long idx = (long)which * 8388608 +
                     ((long)((b * 16 + h) * 2048 + s)) * 64 + c8 * 8;
          *(uint4*)(&Cb[idx]) = v;
        }
      }
    }
  }
}

// ---------------------------------------------------------------------------
// Flash attention, causal + pad mask, fixed softmax cap (scores bounded ~±7).
// Q prescaled by 1/sqrt(D). Q,K: [B*H, S, 64] bf16 ; VT: [B*H, 64, S] bf16 ;
// O: [B*S, 1024] bf16.
//
// r10 post-mortem: r8's persistent vf[2][4] (32 VGPR live across the barrier
// + QK peak) spilled -> WRITE_SIZE 16.4->62.5MB, dur 74->137us. The
// single-barrier Ks[2] schedule itself was never falsified.
// r11: keep Ks[2] single-barrier; make V TRANSIENT — loaded from global
// (L2-resident 8KB tile, reused by 16 q-blocks/head) right after the
// barrier, before softmax (latency hides under the VALU burst), dead by
// iteration end. Peak pressure no longer overlaps QK's sacc+kf.
// LDS: Ks[2] 19KB + QPs 19KB = 38912B — identical footprint, 3 blk/CU.
// ---------------------------------------------------------------------------
#define BQ 128
#define BKV 64
#define PSTR 76   // 38 dwords/row: quads land on banks +0/24/16/8 -> 2-way max

__global__ __launch_bounds__(256, 3) void attn(
    const unsigned short* __restrict__ Q, const unsigned short* __restrict__ Kt,
    const unsigned short* __restrict__ VT, const int* __restrict__ am,
    unsigned short* __restrict__ O) {
  __shared__ unsigned short QPs[BQ * PSTR];     // 19 KB: Q tile, then per-wave P, then O bounce
  __shared__ unsigned short Ks[2][BKV * PSTR];  // 19 KB: double-buffered K tile
  const int S = 2048, D = 64;
  int tid = threadIdx.x, lane = tid & 63, wid = tid >> 6;
  int l15 = lane & 15, quad = lane >> 4;

  int id = blockIdx.x;
  int s = id >> 8;          // CU slot
  int r = id & 255;
  int bh = r & 63;
  int c = r >> 6;           // 0..3
  int qt;                   // heavy-first: s=0 gets the deepest q-tiles
  switch (s) { case 0: qt = 15 - c; break; case 1: qt = 8 + c; break;
               case 2: qt = 7 - c; break; default: qt = c; }
  int q0 = qt * BQ;
  int b = bh >> 4, h = bh & 15;
  const unsigned short* Qg = Q + (long)bh * S * D;
  const unsigned short* Kg = Kt + (long)bh * S * D;
  const unsigned short* Vg = VT + (long)bh * D * S;
  const int* amg = am + b * S;

  // staging geometry (Q prologue and K loop)
  int row0 = tid >> 3, col0 = (tid & 7) * 8;          // rows 0..31
  int row1 = 32 + (tid >> 3), col1 = col0;            // rows 32..63

  // stage Q tile [128][64] -> padded LDS
#pragma unroll
  for (int rr = 0; rr < 4; rr++) {
    int cc = rr * 256 + tid;
    int row = cc >> 3, col = (cc & 7) * 8;
    *(uint4*)(&QPs[row * PSTR + col]) = *(const uint4*)(Qg + (long)(q0 + row) * D + col);
  }

  // prefetch K tile 0 into registers (overlaps the Q barrier)
  uint4 kreg0 = *(const uint4*)(Kg + (long)row0 * D + col0);
  uint4 kreg1 = *(const uint4*)(Kg + (long)row1 * D + col1);

  __syncthreads();
  bf16x8 qf[2][2];   // each wave reads ONLY its own 32-row slab -> safe to alias P later
#pragma unroll
  for (int i = 0; i < 2; i++)
#pragma unroll
    for (int kk = 0; kk < 2; kk++)
      qf[i][kk] = *(const bf16x8*)(&QPs[(wid * 32 + i * 16 + l15) * PSTR + kk * 32 + quad * 8]);

  // Ks[0] <- tile 0; prefetch K tile 1 into regs
  *(uint4*)(&Ks[0][row0 * PSTR + col0]) = kreg0;
  *(uint4*)(&Ks[0][row1 * PSTR + col1]) = kreg1;
  kreg0 = *(const uint4*)(Kg + (long)(BKV + row0) * D + col0);
  kreg1 = *(const uint4*)(Kg + (long)(BKV + row1) * D + col1);
  __syncthreads();   // Ks[0] visible to all waves

  f32x4 o_acc[2][4] = {};
  float lsum[2][4] = {};   // per-lane partials; reduced once in epilogue

  int tFull = q0 >> 6;          // tiles strictly below the diagonal
  int nt = tFull + 2;           // + 2 diagonal tiles
  for (int t = 0; t < nt; t++) {
    int s0 = t * BKV;
    int cur = t & 1, nxt = cur ^ 1;

    // 1: write NEXT K tile into the alternate buffer (kreg holds tile t+1).
    //    Safe: that buffer's last readers were iter t-1's QK, behind its barrier.
    *(uint4*)(&Ks[nxt][row0 * PSTR + col0]) = kreg0;
    *(uint4*)(&Ks[nxt][row1 * PSTR + col1]) = kreg1;

    // pad-mask bias loads issued before MFMA so they hide under it
    int mvj[4];
#pragma unroll
    for (int j = 0; j < 4; j++) mvj[j] = amg[s0 + j * 16 + l15];

    // 2: S = Q K^T from Ks[cur] (written iter t-1, behind its barrier)
    f32x4 sacc[2][4] = {};
#pragma unroll
    for (int kk = 0; kk < 2; kk++) {
      bf16x8 kf[4];
#pragma unroll
      for (int j = 0; j < 4; j++)
        kf[j] = *(const bf16x8*)(&Ks[cur][(j * 16 + l15) * PSTR + kk * 32 + quad * 8]);
      __builtin_amdgcn_s_setprio(1);
#pragma unroll
      for (int i = 0; i < 2; i++)
#pragma unroll
        for (int j = 0; j < 4; j++)
          sacc[i][j] = __builtin_amdgcn_mfma_f32_16x16x32_bf16(qf[i][kk], kf[j], sacc[i][j], 0, 0, 0);
      __builtin_amdgcn_s_setprio(0);
    }

    // 3: the ONLY barrier of the iteration (all QK reads of Ks[cur] done;
    //    next iter may overwrite it).
    __syncthreads();

    // 4: prefetch K tile t+2 into regs (clamped; landed by next iter's write)
    {
      long s0n = (long)(t + 2) * BKV; if (s0n > S - BKV) s0n = S - BKV;
      kreg0 = *(const uint4*)(Kg + (s0n + row0) * D + col0);
      kreg1 = *(const uint4*)(Kg + (s0n + row1) * D + col1);
    }

    // 4b: V fragments for THIS tile, transient (dead by end of step 6).
    //     Issued before softmax so the L2 latency hides under the VALU burst.
    //     V tile (8KB) is L2-resident: reused by all 16 q-blocks of this head.
    bf16x8 vf[2][4];
#pragma unroll
    for (int kk = 0; kk < 2; kk++)
#pragma unroll
      for (int j = 0; j < 4; j++)
        vf[kk][j] = *(const bf16x8*)(Vg + (long)(j * 16 + l15) * S + s0 + kk * 32 + quad * 8);

    float fb[4];
#pragma unroll
    for (int j = 0; j < 4; j++) fb[j] = mvj[j] ? NEGC : -1e38f;

    // 5: softmax -> per-wave P slab (no cross-wave hazard)
    if (t < tFull) {
#pragma unroll
      for (int i = 0; i < 2; i++)
#pragma unroll
        for (int rr = 0; rr < 4; rr++) {
          int prow = (wid * 32 + i * 16 + quad * 4 + rr) * PSTR;
          float rs = 0.f;
#pragma unroll
          for (int j = 0; j < 4; j++) {
            float p = __builtin_amdgcn_exp2f(fmaf(sacc[i][j][rr], LOG2E, fb[j]));
            unsigned int u = __builtin_bit_cast(unsigned int, p);
            QPs[prow + j * 16 + l15] = (unsigned short)(u >> 16);
            rs += __builtin_bit_cast(float, u & 0xffff0000u);
          }
          lsum[i][rr] += rs;
        }
    } else {
      // diagonal tile: per-element causal mask
#pragma unroll
      for (int i = 0; i < 2; i++)
#pragma unroll
        for (int rr = 0; rr < 4; rr++) {
          int row = q0 + wid * 32 + i * 16 + quad * 4 + rr;
          int prow = (wid * 32 + i * 16 + quad * 4 + rr) * PSTR;
          float rs = 0.f;
#pragma unroll
          for (int j = 0; j < 4; j++) {
            int col = s0 + j * 16 + l15;
            float fbe = (col > row) ? -1e38f : fb[j];
            float p = __builtin_amdgcn_exp2f(fmaf(sacc[i][j][rr], LOG2E, fbe));
            unsigned int u = __builtin_bit_cast(unsigned int, p);
            QPs[prow + j * 16 + l15] = (unsigned short)(u >> 16);
            rs += __builtin_bit_cast(float, u & 0xffff0000u);
          }
          lsum[i][rr] += rs;
        }
    }

    // 6: O += P @ V  (P LDS round-trip; V fragments in regs, loaded at 4b)
#pragma unroll
    for (int kk = 0; kk < 2; kk++) {
      bf16x8 pf[2];
#pragma unroll
      for (int i = 0; i < 2; i++)
        pf[i] = *(const bf16x8*)(&QPs[(wid * 32 + i * 16 + l15) * PSTR + kk * 32 + quad * 8]);
      __builtin_amdgcn_s_setprio(1);
#pragma unroll
      for (int i = 0; i < 2; i++)
#pragma unroll
        for (int j = 0; j < 4; j++)
          o_acc[i][j] = __builtin_amdgcn_mfma_f32_16x16x32_bf16(pf[i], vf[kk][j], o_acc[i][j], 0, 0, 0);
      __builtin_amdgcn_s_setprio(0);
    }
  }

  // epilogue: reduce lsum across the 16 col-lanes, normalize, bounce through
  // LDS (P layout), then bulk-store full 128B lines.
#pragma unroll
  for (int i = 0; i < 2; i++)
#pragma unroll
    for (int rr = 0; rr < 4; rr++) {
      float tsum = lsum[i][rr];
      tsum += __shfl_xor(tsum, 1, 64);
      tsum += __shfl_xor(tsum, 2, 64);
      tsum += __shfl_xor(tsum, 4, 64);
      tsum += __shfl_xor(tsum, 8, 64);
      float inv = 1.0f / tsum;
      int prow = (wid * 32 + i * 16 + quad * 4 + rr) * PSTR;
#pragma unroll
      for (int j = 0; j < 4; j++)
        QPs[prow + j * 16 + l15] = f2bf(o_acc[i][j][rr] * inv);
    }
  __syncthreads();
#pragma unroll
  for (int rr = 0; rr < 4; rr++) {
    int cc = rr * 256 + tid;
    int row = cc >> 3, col = (cc & 7) * 8;
    uint4 v = *(const uint4*)(&QPs[row * PSTR + col]);
    long gm = (long)b * S + q0 + row;
    *(uint4*)(&O[gm * 1024 + h * 64 + col]) = v;
  }
}

extern "C" void kernel_launch(void* const* d_in, const int* in_sizes, int n_in,
                              void* d_out, int out_size, void* d_ws, size_t ws_size,
                              hipStream_t stream) {
  const float* x  = (const float*)d_in[0];
  const int*   am = (const int*)d_in[1];
  const float* wq = (const float*)d_in[2];
  const float* wk = (const float*)d_in[3];
  const float* wv = (const float*)d_in[4];
  const float* wo = (const float*)d_in[5];
  float* out = (float*)d_out;

  const int S = 2048, E = 1024, Bb = 4, H = 16;
  const int M = Bb * S;  // 8192

  char* ws = (char*)d_ws;
  unsigned short* xb  = (unsigned short*)ws;                    // 16 MiB
  unsigned short* wqb = (unsigned short*)(ws + 16777216);       // 2 MiB each, contiguous
  unsigned short* wob = wqb + 3 * 1048576;
  unsigned short* Qb  = (unsigned short*)(ws + 25165824);       // Q,K,VT contiguous 16 MiB each
  unsigned short* Ob  = Qb + 25165824;                          // end: 88 MiB

  // all casts in one launch: x (8192 blocks) + 4 weights (1024 each)
  cast_all<<<12288, 256, 0, stream>>>(x, wq, wk, wv, wo, xb, wqb);

  // fused QKV projection: W = [wq;wk;wv] contiguous, N=3072 (1-D swizzled grid).
  gemm_bt<<<dim3((3 * E / BN) * (M / BM)), 256, 0, stream>>>(xb, wqb, Qb, M, 3 * E, E, 4);
  attn<<<dim3(1024), 256, 0, stream>>>(Qb, Qb + 8388608, Qb + 16777216, am, Ob);
  gemm_bt<<<dim3((E / BN) * (M / BM)), 256, 0, stream>>>(Ob, wob, out, M, E, E, 0);  // final proj, f32
}

// Round 13
// 241.538 us; speedup vs baseline: 1.2742x; 1.1415x over previous
//
#include <hip/hip_runtime.h>

typedef __bf16 bf16x8 __attribute__((ext_vector_type(8)));
typedef float f32x4 __attribute__((ext_vector_type(4)));

#define LOG2E 1.4426950408889634f
#define NEGC (-12.0f * LOG2E)   // fixed softmax cap C=12 in log2 units

__device__ inline unsigned short f2bf(float f) {
  unsigned int u = __builtin_bit_cast(unsigned int, f);
  u += 0x7fff + ((u >> 16) & 1);
  return (unsigned short)(u >> 16);
}

__device__ inline void async16(const void* g, void* l) {
  __builtin_amdgcn_global_load_lds(
      (__attribute__((address_space(1))) void*)(g),
      (__attribute__((address_space(3))) void*)(l), 16, 0, 0);
}

// One launch for all f32->bf16 casts: blocks [0,8192) cover x (8M elems),
// blocks [8192,12288) cover the 4 weight matrices (1M elems each).
__global__ __launch_bounds__(256) void cast_all(
    const float* __restrict__ x, const float* __restrict__ w0,
    const float* __restrict__ w1, const float* __restrict__ w2,
    const float* __restrict__ w3, unsigned short* __restrict__ xb,
    unsigned short* __restrict__ ob /* 4 contiguous 1M outputs */) {
  int id = blockIdx.x;
  const float* in;
  unsigned short* out;
  int boff;
  if (id < 8192) { in = x; out = xb; boff = id; }
  else {
    int w = (id - 8192) >> 10; boff = (id - 8192) & 1023;
    switch (w) { case 0: in = w0; break; case 1: in = w1; break;
                 case 2: in = w2; break; default: in = w3; }
    out = ob + (long)w * 1048576;
  }
  int i = (boff * 256 + threadIdx.x) * 4;
  float4 v = *(const float4*)(in + i);
  ushort4 o;
  o.x = f2bf(v.x); o.y = f2bf(v.y); o.z = f2bf(v.z); o.w = f2bf(v.w);
  *(ushort4*)(out + i) = o;
}

// ---------------------------------------------------------------------------
// 128x128 GEMM (m97 2-barrier structure), harness-proven. QKV (mode 4) and
// final projection (mode 0).
// C[M,N] = A[M,K] * W[N,K]^T, bf16 in. Launched 1-D; M/BM must be 64.
// mode 0: f32 row-major [M,N]
// mode 4: fused QKV scatter. Q (x0.125) and K -> [B,H,S,D]. V -> V^T [B,H,D,S].
// r6: Q/K epilogue bounces through LDS (aliases dead As/Ws) -> uint4 stores.
// ---------------------------------------------------------------------------
#define BM 128
#define BN 128
#define BK 32

__global__ __launch_bounds__(256, 3) void gemm_bt(
    const unsigned short* __restrict__ A, const unsigned short* __restrict__ W,
    void* __restrict__ out, int M, int N, int K, int mode) {
  __shared__ unsigned short SM[BM * BK + BN * BK];  // As | Ws, 16 KB total
  unsigned short* As = SM;
  unsigned short* Ws = SM + BM * BK;
  int tid = threadIdx.x;
  int lane = tid & 63, wid = tid >> 6;
  int wm = wid >> 1, wn = wid & 1;
  int l15 = lane & 15, quad = lane >> 4;
  int m0 = (blockIdx.x & 63) * BM, n0 = (blockIdx.x >> 6) * BN;

  f32x4 acc[4][4] = {};

  int srow = tid >> 2;         // 0..63
  int scol = (tid & 3) * 8;    // 0,8,16,24
  const unsigned short* Ag = A + (long)(m0 + srow) * K + scol;
  const unsigned short* Wg = W + (long)(n0 + srow) * K + scol;
  char* AsB = (char*)As + wid * 1024;   // + lane*16 implicit in global_load_lds
  char* WsB = (char*)Ws + wid * 1024;

  for (int kt = 0; kt < K; kt += BK) {
    __syncthreads();
    async16(Ag + kt, AsB);
    async16(Ag + kt + (long)64 * K, AsB + 4096);
    async16(Wg + kt, WsB);
    async16(Wg + kt + (long)64 * K, WsB + 4096);
    __syncthreads();
    bf16x8 af[4], wf[4];
#pragma unroll
    for (int t = 0; t < 4; t++)
      af[t] = *(const bf16x8*)(As + (wm * 64 + t * 16 + l15) * BK + quad * 8);
#pragma unroll
    for (int t = 0; t < 4; t++)
      wf[t] = *(const bf16x8*)(Ws + (wn * 64 + t * 16 + l15) * BK + quad * 8);
#pragma unroll
    for (int i = 0; i < 4; i++)
#pragma unroll
      for (int j = 0; j < 4; j++)
        acc[i][j] = __builtin_amdgcn_mfma_f32_16x16x32_bf16(af[i], wf[j], acc[i][j], 0, 0, 0);
  }

  if (mode == 0) {
    float* Cf = (float*)out;
#pragma unroll
    for (int i = 0; i < 4; i++) {
      int row = m0 + wm * 64 + i * 16 + quad * 4;
#pragma unroll
      for (int j = 0; j < 4; j++) {
        int col = n0 + wn * 64 + j * 16 + l15;
#pragma unroll
        for (int r = 0; r < 4; r++)
          Cf[(long)(row + r) * N + col] = acc[i][j][r];
      }
    }
  } else {
    unsigned short* Cb = (unsigned short*)out;
    int which = n0 >> 10;   // block lies entirely in one of Q/K/V
    if (which == 2) {
      // V -> V^T [B,H,D,S]: packed 4-consecutive-s stores (8B/lane)
#pragma unroll
      for (int i = 0; i < 4; i++)
#pragma unroll
        for (int j = 0; j < 4; j++) {
          int m = m0 + wm * 64 + i * 16 + quad * 4;
          int n = n0 + wn * 64 + j * 16 + l15;
          int nn = n & 1023;
          int b = m >> 11, s = m & 2047;   // S = 2048 (block never crosses b)
          int h = nn >> 6, d = nn & 63;    // D = 64
          ushort4 pk;
          pk.x = f2bf(acc[i][j][0]); pk.y = f2bf(acc[i][j][1]);
          pk.z = f2bf(acc[i][j][2]); pk.w = f2bf(acc[i][j][3]);
          *(ushort4*)(&Cb[16777216 + (((long)((b * 16 + h) * 64 + d)) << 11) + s]) = pk;
        }
    } else {
      // Q/K -> [B,H,S,D] via LDS bounce (quarters of 32 rows through SM).
      float scale = (which == 0) ? 0.125f : 1.0f;
      int h0 = (n0 & 1023) >> 6;
      unsigned short* Es = SM;    // 32 x 136 = 8704 B, aliases dead As/Ws
#pragma unroll
      for (int qr = 0; qr < 4; qr++) {
        __syncthreads();          // K-loop / previous quarter reads done
        if (wm == (qr >> 1)) {    // wave-uniform predicate
#pragma unroll
          for (int ii = 0; ii < 2; ii++) {
            int i = (qr & 1) * 2 + ii;      // rows wm*64 + i*16 + .. in quarter
#pragma unroll
            for (int j = 0; j < 4; j++)
#pragma unroll
              for (int r = 0; r < 4; r++) {
                int rr = (i & 1) * 16 + quad * 4 + r;   // row within quarter
                Es[rr * 136 + wn * 64 + j * 16 + l15] = f2bf(acc[i][j][r] * scale);
              }
          }
        }
        __syncthreads();
#pragma unroll
        for (int p = 0; p < 2; p++) {
          int pair = p * 32 + (tid >> 3);   // 0..63: (row-in-quarter, head)
          int rq = pair >> 1;
          int head = pair & 1, c8 = tid & 7;
          uint4 v = *(const uint4*)(&Es[rq * 136 + head * 64 + c8 * 8]);
          int m = m0 + qr * 32 + rq;
          int b = m >> 11, s = m & 2047;    // S = 2048
          int h = h0 + head;
          long idx = (long)which * 8388608 +
                     ((long)((b * 16 + h) * 2048 + s)) * 64 + c8 * 8;
          *(uint4*)(&Cb[idx]) = v;
        }
      }
    }
  }
}

// ---------------------------------------------------------------------------
// Flash attention, causal + pad mask, fixed softmax cap (scores bounded ~±7).
// Q prescaled by 1/sqrt(D). Q,K: [B*H, S, 64] bf16 ; VT: [B*H, 64, S] bf16 ;
// O: [B*S, 1024] bf16.
//
// r13: SWAPPED QK^T (T12 direction). Compute S^T = mfma(K, Q): lane(l15,quad)
// reg r of sacc[i][j] = S[q=i*16+l15][kv=j*16+quad*4+r] -> the lane's 4 regs
// are kv-CONTIGUOUS. P packs into ONE ds_write_b64 per (i,j): 8 vector writes
// replace 32 scalar ds_write_u16 (-24 LDS ops/iter). P-slab layout [q][kv]
// preserved -> PV's pf ds_read_b128 unchanged. K/Q/V fragments are layout-
// symmetric (A/B frags both row|col=l15, k=quad*8) -> staging untouched.
// Pad mask via __ballot (bit kv = am[s0+kv]!=0), lsum[2][4]->[2] (-6 VGPR).
// Epilogue: reduce over quads (shfl_xor 16,32), inv via dynamic shfl.
// Prior anchor (r7-measured): 74us, VGPR 84, WRITE 16.4MB, MfmaUtil 20.
// ---------------------------------------------------------------------------
#define BQ 128
#define BKV 64
#define PSTR 76   // 38 dwords/row: quads land on banks +0/24/16/8 -> 2-way max

__global__ __launch_bounds__(256, 3) void attn(
    const unsigned short* __restrict__ Q, const unsigned short* __restrict__ Kt,
    const unsigned short* __restrict__ VT, const int* __restrict__ am,
    unsigned short* __restrict__ O) {
  __shared__ unsigned short QPs[BQ * PSTR];   // 19 KB: Q tile, then per-wave P, then O bounce
  __shared__ unsigned short Ks[BKV * PSTR];   // 9.5 KB
  __shared__ unsigned short Vs[64 * PSTR];    // 9.5 KB [d][s]
  const int S = 2048, D = 64;
  int tid = threadIdx.x, lane = tid & 63, wid = tid >> 6;
  int l15 = lane & 15, quad = lane >> 4;

  int id = blockIdx.x;
  int s = id >> 8;          // CU slot
  int r = id & 255;
  int bh = r & 63;
  int c = r >> 6;           // 0..3
  int qt;                   // heavy-first: s=0 gets the deepest q-tiles
  switch (s) { case 0: qt = 15 - c; break; case 1: qt = 8 + c; break;
               case 2: qt = 7 - c; break; default: qt = c; }
  int q0 = qt * BQ;
  int b = bh >> 4, h = bh & 15;
  const unsigned short* Qg = Q + (long)bh * S * D;
  const unsigned short* Kg = Kt + (long)bh * S * D;
  const unsigned short* Vg = VT + (long)bh * D * S;
  const int* amg = am + b * S;

  // staging geometry (shared by Q prologue and K/V loop)
  int row0 = tid >> 3, col0 = (tid & 7) * 8;          // rows 0..31
  int row1 = 32 + (tid >> 3), col1 = col0;            // rows 32..63

  // stage Q tile [128][64] -> padded LDS
#pragma unroll
  for (int rr = 0; rr < 4; rr++) {
    int cc = rr * 256 + tid;
    int row = cc >> 3, col = (cc & 7) * 8;
    *(uint4*)(&QPs[row * PSTR + col]) = *(const uint4*)(Qg + (long)(q0 + row) * D + col);
  }

  // prefetch K/V tile 0 into registers (overlaps the Q barrier)
  uint4 kreg0 = *(const uint4*)(Kg + (long)row0 * D + col0);
  uint4 kreg1 = *(const uint4*)(Kg + (long)row1 * D + col1);
  uint4 vreg0 = *(const uint4*)(Vg + (long)row0 * S + col0);
  uint4 vreg1 = *(const uint4*)(Vg + (long)row1 * S + col1);

  __syncthreads();
  bf16x8 qf[2][2];   // each wave reads ONLY its own 32-row slab -> safe to alias P later
#pragma unroll
  for (int i = 0; i < 2; i++)
#pragma unroll
    for (int kk = 0; kk < 2; kk++)
      qf[i][kk] = *(const bf16x8*)(&QPs[(wid * 32 + i * 16 + l15) * PSTR + kk * 32 + quad * 8]);

  f32x4 o_acc[2][4] = {};
  float lsum[2] = {};   // per-lane partial denominators for q = i*16+l15

  int tFull = q0 >> 6;          // tiles strictly below the diagonal
  int nt = tFull + 2;           // + 2 diagonal tiles
  for (int t = 0; t < nt; t++) {
    int s0 = t * BKV;
    __syncthreads();   // all waves done reading previous K/V LDS tile
    *(uint4*)(&Ks[row0 * PSTR + col0]) = kreg0;
    *(uint4*)(&Ks[row1 * PSTR + col1]) = kreg1;
    *(uint4*)(&Vs[row0 * PSTR + col0]) = vreg0;
    *(uint4*)(&Vs[row1 * PSTR + col1]) = vreg1;
    __syncthreads();

    // issue prefetch for tile t+1 NOW; latency hides under this tile's compute.
    // Clamp: t+1==nt row is loaded but never consumed (stays in-bounds).
    {
      long s0n = (t + 1) * BKV; if (s0n > S - BKV) s0n = S - BKV;
      kreg0 = *(const uint4*)(Kg + (s0n + row0) * D + col0);
      kreg1 = *(const uint4*)(Kg + (s0n + row1) * D + col1);
      vreg0 = *(const uint4*)(Vg + (long)row0 * S + s0n + col0);
      vreg1 = *(const uint4*)(Vg + (long)row1 * S + s0n + col1);
    }

    // pad-mask load (1 int per lane, kv = lane) issued before MFMA
    int amv = amg[s0 + lane];

    // S^T = K Q^T  (swapped operands: sacc[i][j][r] = S[q=i*16+l15][kv=j*16+quad*4+r])
    f32x4 sacc[2][4] = {};
#pragma unroll
    for (int kk = 0; kk < 2; kk++) {
      bf16x8 kf[4];
#pragma unroll
      for (int j = 0; j < 4; j++)
        kf[j] = *(const bf16x8*)(&Ks[(j * 16 + l15) * PSTR + kk * 32 + quad * 8]);
      __builtin_amdgcn_s_setprio(1);
#pragma unroll
      for (int i = 0; i < 2; i++)
#pragma unroll
        for (int j = 0; j < 4; j++)
          sacc[i][j] = __builtin_amdgcn_mfma_f32_16x16x32_bf16(kf[j], qf[i][kk], sacc[i][j], 0, 0, 0);
      __builtin_amdgcn_s_setprio(0);
    }

    // bit kv of bal = pad-valid(kv)
    unsigned long long bal = __ballot(amv != 0);

    // softmax: p = exp2(v*log2e + fb); pack 4 kv-contiguous bf16 -> ds_write_b64.
    // Sum the SAME truncated values so num/denom bias cancels exactly.
    if (t < tFull) {
#pragma unroll
      for (int i = 0; i < 2; i++) {
        float rs = 0.f;
#pragma unroll
        for (int j = 0; j < 4; j++) {
          unsigned nib = (unsigned)(bal >> (j * 16 + quad * 4)) & 15u;
          unsigned v[4];
#pragma unroll
          for (int r = 0; r < 4; r++) {
            float fbe = ((nib >> r) & 1) ? NEGC : -1e38f;
            float p = __builtin_amdgcn_exp2f(fmaf(sacc[i][j][r], LOG2E, fbe));
            v[r] = __builtin_bit_cast(unsigned, p) & 0xffff0000u;
            rs += __builtin_bit_cast(float, v[r]);
          }
          uint2 pk;
          pk.x = (v[0] >> 16) | v[1];
          pk.y = (v[2] >> 16) | v[3];
          *(uint2*)(&QPs[(wid * 32 + i * 16 + l15) * PSTR + j * 16 + quad * 4]) = pk;
        }
        lsum[i] += rs;
      }
    } else {
      // diagonal tile: per-element causal mask (kv > q -> -inf)
#pragma unroll
      for (int i = 0; i < 2; i++) {
        int qrow = q0 + wid * 32 + i * 16 + l15;
        float rs = 0.f;
#pragma unroll
        for (int j = 0; j < 4; j++) {
          unsigned nib = (unsigned)(bal >> (j * 16 + quad * 4)) & 15u;
          unsigned v[4];
#pragma unroll
          for (int r = 0; r < 4; r++) {
            int kv = s0 + j * 16 + quad * 4 + r;
            float fbe = (((nib >> r) & 1) && kv <= qrow) ? NEGC : -1e38f;
            float p = __builtin_amdgcn_exp2f(fmaf(sacc[i][j][r], LOG2E, fbe));
            v[r] = __builtin_bit_cast(unsigned, p) & 0xffff0000u;
            rs += __builtin_bit_cast(float, v[r]);
          }
          uint2 pk;
          pk.x = (v[0] >> 16) | v[1];
          pk.y = (v[2] >> 16) | v[3];
          *(uint2*)(&QPs[(wid * 32 + i * 16 + l15) * PSTR + j * 16 + quad * 4]) = pk;
        }
        lsum[i] += rs;
      }
    }

    // O += P @ V   (P LDS round-trip; same-wave DS ops are in-order)
#pragma unroll
    for (int kk = 0; kk < 2; kk++) {
      bf16x8 pf[2], vf[4];
#pragma unroll
      for (int i = 0; i < 2; i++)
        pf[i] = *(const bf16x8*)(&QPs[(wid * 32 + i * 16 + l15) * PSTR + kk * 32 + quad * 8]);
#pragma unroll
      for (int j = 0; j < 4; j++)
        vf[j] = *(const bf16x8*)(&Vs[(j * 16 + l15) * PSTR + kk * 32 + quad * 8]);
      __builtin_amdgcn_s_setprio(1);
#pragma unroll
      for (int i = 0; i < 2; i++)
#pragma unroll
        for (int j = 0; j < 4; j++)
          o_acc[i][j] = __builtin_amdgcn_mfma_f32_16x16x32_bf16(pf[i], vf[j], o_acc[i][j], 0, 0, 0);
      __builtin_amdgcn_s_setprio(0);
    }
  }

  // epilogue: reduce lsum over the 4 quads (each covers a disjoint 16 of 64 kv
  // per q=l15), redistribute inv to o_acc rows (q=quad*4+rr) via dynamic shfl,
  // normalize, bounce through LDS, bulk-store 128B lines.
#pragma unroll
  for (int i = 0; i < 2; i++) {
    float ts = lsum[i];
    ts += __shfl_xor(ts, 16, 64);
    ts += __shfl_xor(ts, 32, 64);
#pragma unroll
    for (int rr = 0; rr < 4; rr++) {
      float inv = 1.0f / __shfl(ts, quad * 4 + rr, 64);
      int prow = (wid * 32 + i * 16 + quad * 4 + rr) * PSTR;
#pragma unroll
      for (int j = 0; j < 4; j++)
        QPs[prow + j * 16 + l15] = f2bf(o_acc[i][j][rr] * inv);
    }
  }
  __syncthreads();
#pragma unroll
  for (int rr = 0; rr < 4; rr++) {
    int cc = rr * 256 + tid;
    int row = cc >> 3, col = (cc & 7) * 8;
    uint4 v = *(const uint4*)(&QPs[row * PSTR + col]);
    long gm = (long)b * S + q0 + row;
    *(uint4*)(&O[gm * 1024 + h * 64 + col]) = v;
  }
}

extern "C" void kernel_launch(void* const* d_in, const int* in_sizes, int n_in,
                              void* d_out, int out_size, void* d_ws, size_t ws_size,
                              hipStream_t stream) {
  const float* x  = (const float*)d_in[0];
  const int*   am = (const int*)d_in[1];
  const float* wq = (const float*)d_in[2];
  const float* wk = (const float*)d_in[3];
  const float* wv = (const float*)d_in[4];
  const float* wo = (const float*)d_in[5];
  float* out = (float*)d_out;

  const int S = 2048, E = 1024, Bb = 4, H = 16;
  const int M = Bb * S;  // 8192

  char* ws = (char*)d_ws;
  unsigned short* xb  = (unsigned short*)ws;                    // 16 MiB
  unsigned short* wqb = (unsigned short*)(ws + 16777216);       // 2 MiB each, contiguous
  unsigned short* wob = wqb + 3 * 1048576;
  unsigned short* Qb  = (unsigned short*)(ws + 25165824);       // Q,K,VT contiguous 16 MiB each
  unsigned short* Ob  = Qb + 25165824;                          // end: 88 MiB

  // all casts in one launch: x (8192 blocks) + 4 weights (1024 each)
  cast_all<<<12288, 256, 0, stream>>>(x, wq, wk, wv, wo, xb, wqb);

  // fused QKV projection: W = [wq;wk;wv] contiguous, N=3072 (1-D swizzled grid).
  gemm_bt<<<dim3((3 * E / BN) * (M / BM)), 256, 0, stream>>>(xb, wqb, Qb, M, 3 * E, E, 4);
  attn<<<dim3(1024), 256, 0, stream>>>(Qb, Qb + 8388608, Qb + 16777216, am, Ob);
  gemm_bt<<<dim3((E / BN) * (M / BM)), 256, 0, stream>>>(Ob, wob, out, M, E, E, 0);  // final proj, f32
}